// Round 7
// baseline (395.766 us; speedup 1.0000x reference)
//
#include <hip/hip_runtime.h>

#define BB 8
#define TT 128
#define DD 256
#define BT (BB * TT)       // 1024 (b,t) pairs
#define LOG2E 1.44269504088896340736f

// R12: M-once via rotation + conflict-free LDS atomics, ZERO main-loop
// barriers (R11's 16-barrier stripe structure cost +33us of serialization).
// Thread q owns column q of M[p][q]=exp2(d_p*el2_q): colsum is a local add.
// Row coverage rotates: at step J (0..63), thread q computes rows
// p = 4*((q>>2)+J) + ((q+i)&3), i=0..3  (each (p,q) exactly once; at any
// instant all lanes hit DISTINCT rows -> ds_add_f32 conflict-free).
// Four pre-rotated, doubled copies of d in LDS make the per-step read a
// single aligned ds_read_b128 with immediate-offset walk (no per-step addr
// VALU). Rowsum lands in a doubled accumulator racc[512] (index un-modded;
// aliases combined at the end). Per 4 elements: 1 ds_read(12) + 4 mul +
// 4 exp(96) + 4 add + 4 ds_add(~32) ~= 160cyc vs R5's 224 -- and E halves.
__global__ __launch_bounds__(256, 4) void attn_rot_kernel(
    const float* __restrict__ dec,   // [B, D]
    const float* __restrict__ enc,   // [B, T, D]
    float* __restrict__ ws) {        // [BT, D] per-(b,t) contributions
    const int blk = blockIdx.x;              // b*TT + t
    const int b = blk >> 7;
    const int tid = threadIdx.x;             // q

    const float* __restrict__ drow = dec + b * DD;    // uniform pointer
    const float* __restrict__ erow = enc + blk * DD;  // uniform pointer

    __shared__ float drot[4][512];   // 4 rotations x doubled d (8 KB)
    __shared__ float racc[512];      // doubled rowsum accumulators (2 KB)

    // zero accumulators (incl. never-written tail entries 508..511)
    racc[tid] = 0.f;
    racc[tid + 256] = 0.f;

    // rotated+doubled d copies: drot[r][4k+i] = d[(4k + ((i+r)&3)) mod 256]
    #pragma unroll
    for (int r = 0; r < 4; ++r) {
        #pragma unroll
        for (int c = 0; c < 2; ++c) {
            const int e = tid + 256 * c;
            const int k = e >> 2, i = e & 3;
            drot[r][e] = drow[(4 * k + ((i + r) & 3)) & 255];
        }
    }

    const float ev = erow[tid];            // per-lane
    const float el2 = ev * LOG2E;          // M[p][q] = exp2(d_p * el2)
    const int rot = tid & 3;
    const int qb = tid >> 2;
    // fixed accumulator bases for the 4 sub-rows (offset 4J added per step)
    const int a0 = 4 * qb + ((tid + 0) & 3);
    const int a1 = 4 * qb + ((tid + 1) & 3);
    const int a2 = 4 * qb + ((tid + 2) & 3);
    const int a3 = 4 * qb + ((tid + 3) & 3);
    const float* dptr = &drot[rot][4 * qb];   // 16B-aligned walk base

    __syncthreads();   // drot + racc ready

    float cs0 = 0.f, cs1 = 0.f, cs2 = 0.f, cs3 = 0.f;
    #pragma unroll 8
    for (int J = 0; J < 64; ++J) {
        float4 d4 = *reinterpret_cast<const float4*>(dptr + 4 * J);  // ds_read_b128
        const float v0 = __builtin_amdgcn_exp2f(d4.x * el2);
        const float v1 = __builtin_amdgcn_exp2f(d4.y * el2);
        const float v2 = __builtin_amdgcn_exp2f(d4.z * el2);
        const float v3 = __builtin_amdgcn_exp2f(d4.w * el2);
        cs0 += v0; cs1 += v1; cs2 += v2; cs3 += v3;       // colsum (own q)
        atomicAdd(&racc[a0 + 4 * J], v0);   // ds_add_f32, distinct rows/lane
        atomicAdd(&racc[a1 + 4 * J], v1);
        atomicAdd(&racc[a2 + 4 * J], v2);
        atomicAdd(&racc[a3 + 4 * J], v3);
    }
    __syncthreads();   // all atomics visible

    const float cs = (cs0 + cs1) + (cs2 + cs3);
    const float rs = racc[tid] + racc[tid + 256];   // combine the two aliases
    ws[blk * DD + tid] = ev * cs / rs;
}

// Phase 2 (proven): 64 blocks = (b, 32-wide q-slice); 256 threads =
// 8 t-chunks (16 t each) x 32 q. Lanes read consecutive q -> coalesced;
// ws is L2-resident (1 MB).
__global__ __launch_bounds__(256) void reduce_t_kernel(
    const float* __restrict__ ws, float* __restrict__ out) {
    __shared__ float red[8][32];
    const int b = blockIdx.x >> 3;
    const int qc = blockIdx.x & 7;
    const int qlane = threadIdx.x & 31;
    const int tc = threadIdx.x >> 5;         // 0..7
    const int q = qc * 32 + qlane;

    const float* p = ws + (b * TT + tc * 16) * DD + q;
    float a0 = 0.f, a1 = 0.f, a2 = 0.f, a3 = 0.f;
    #pragma unroll
    for (int t = 0; t < 16; t += 4) {
        a0 += p[(t + 0) * DD];
        a1 += p[(t + 1) * DD];
        a2 += p[(t + 2) * DD];
        a3 += p[(t + 3) * DD];
    }
    red[tc][qlane] = (a0 + a1) + (a2 + a3);
    __syncthreads();
    if (tc == 0) {
        float s = 0.f;
        #pragma unroll
        for (int u = 0; u < 8; ++u) s += red[u][qlane];
        out[b * DD + q] = s;
    }
}

extern "C" void kernel_launch(void* const* d_in, const int* in_sizes, int n_in,
                              void* d_out, int out_size, void* d_ws, size_t ws_size,
                              hipStream_t stream) {
    const float* dec = (const float*)d_in[0];  // [B, D] fp32
    const float* enc = (const float*)d_in[1];  // [B, T, D] fp32
    float* out = (float*)d_out;                // [B, D] fp32
    float* ws = (float*)d_ws;                  // >= BT*DD floats (1 MB)

    attn_rot_kernel<<<BT, 256, 0, stream>>>(dec, enc, ws);
    reduce_t_kernel<<<BB * 8, 256, 0, stream>>>(ws, out);
}

// Round 8
// 81.659 us; speedup vs baseline: 4.8466x; 4.8466x over previous
//
#include <hip/hip_runtime.h>

#define BB 8
#define TT 128
#define DD 256
#define BT (BB * TT)       // 1024 (b,t) pairs
#define SZ (BT * DD)       // 262144 floats per partial plane
#define K0 160             // trans-method k-range [0,K0); poly [K0,256)
#define LOG2E 1.44269504088896340736f

// R13: hybrid TRANS+VALU across blocks. Model (fits R5..R12): phase1 is
// throughput-bound at ~24cyc per v_exp_f32 wave-instr per SIMD (occupancy-
// invariant, R10); VALU-poly exp costs ~46cyc/elem on the VALU pipe (R8).
// Same-wave mixing serializes (R9). UNTESTED: cross-wave overlap of the
// trans unit with VALU issue (m114 precedent: MFMA||VALU across waves = max
// not sum). Split the k-range into a trans plane [0,160) and a poly plane
// [160,256) computed by SEPARATE co-resident blocks (parity-interleaved ->
// every CU hosts ~4 trans + 4 poly blocks). If overlap holds: phase1
// 23.4 -> ~15us. Plane-combine in phase2 proven in R10.
__device__ __forceinline__ float exp2_fast(float z) {
    const float r = __builtin_rintf(z);          // v_rndne_f32
    const float f = z - r;                       // f in [-0.5, 0.5]
    float p = 1.5252733804059840e-5f;            // ln2^7/7!
    p = __builtin_fmaf(p, f, 1.5403530393381609e-4f);
    p = __builtin_fmaf(p, f, 1.3333558146428443e-3f);
    p = __builtin_fmaf(p, f, 9.6181291076284772e-3f);
    p = __builtin_fmaf(p, f, 5.5504108664821580e-2f);
    p = __builtin_fmaf(p, f, 2.4022650695910072e-1f);
    p = __builtin_fmaf(p, f, 6.9314718055994531e-1f);
    p = __builtin_fmaf(p, f, 1.0f);
    return ldexpf(p, (int)r);                    // v_cvt_i32 + v_ldexp_f32
}

__global__ __launch_bounds__(256, 8) void attn_hybrid_kernel(
    const float* __restrict__ dec,   // [B, D]
    const float* __restrict__ enc,   // [B, T, D]
    float* __restrict__ ws) {        // [4][BT][DD]: {cs_t, cs_p, rs_t, rs_p}
    const int blk2 = blockIdx.x;         // 0..2047
    const int blk  = blk2 >> 1;          // b*TT + t
    const int meth = blk2 & 1;           // 0 = trans pipe, 1 = VALU poly
    const int b    = blk >> 7;
    const int tid  = threadIdx.x;        // q

    const float* __restrict__ drow = dec + b * DD;    // uniform pointer
    const float* __restrict__ erow = enc + blk * DD;  // uniform pointer

    const float dv = drow[tid];            // per-lane
    const float ev = erow[tid];            // per-lane
    const float dl2 = dv * LOG2E;          // rowsum arg: exp2(dl2 * e_r)
    const float el2 = ev * LOG2E;          // colsum arg: exp2(d_p * el2)

    float cs0 = 0.f, cs1 = 0.f, cs2 = 0.f, cs3 = 0.f;
    float rs0 = 0.f, rs1 = 0.f, rs2 = 0.f, rs3 = 0.f;

    if (meth == 0) {
        // TRANS-pipe method (R5 body), k in [0, K0)
        #pragma unroll 4
        for (int k = 0; k < K0; k += 4) {
            float4 d4 = *reinterpret_cast<const float4*>(drow + k);
            float4 e4 = *reinterpret_cast<const float4*>(erow + k);
            cs0 += __builtin_amdgcn_exp2f(d4.x * el2);
            cs1 += __builtin_amdgcn_exp2f(d4.y * el2);
            cs2 += __builtin_amdgcn_exp2f(d4.z * el2);
            cs3 += __builtin_amdgcn_exp2f(d4.w * el2);
            rs0 += __builtin_amdgcn_exp2f(dl2 * e4.x);
            rs1 += __builtin_amdgcn_exp2f(dl2 * e4.y);
            rs2 += __builtin_amdgcn_exp2f(dl2 * e4.z);
            rs3 += __builtin_amdgcn_exp2f(dl2 * e4.w);
        }
    } else {
        // VALU-poly method (R8 body), k in [K0, 256)
        #pragma unroll 4
        for (int k = K0; k < DD; k += 4) {
            float4 d4 = *reinterpret_cast<const float4*>(drow + k);
            float4 e4 = *reinterpret_cast<const float4*>(erow + k);
            cs0 += exp2_fast(d4.x * el2);
            cs1 += exp2_fast(d4.y * el2);
            cs2 += exp2_fast(d4.z * el2);
            cs3 += exp2_fast(d4.w * el2);
            rs0 += exp2_fast(dl2 * e4.x);
            rs1 += exp2_fast(dl2 * e4.y);
            rs2 += exp2_fast(dl2 * e4.z);
            rs3 += exp2_fast(dl2 * e4.w);
        }
    }

    const int o = blk * DD + tid;
    ws[meth * SZ + o]       = (cs0 + cs1) + (cs2 + cs3);  // colsum partial
    ws[(2 + meth) * SZ + o] = (rs0 + rs1) + (rs2 + rs3);  // rowsum partial
}

// Phase 2 (proven R10): 64 blocks = (b, 32-wide q-slice); 256 threads =
// 8 t-chunks (16 t each) x 32 q. Combines the k-planes (division is
// nonlinear -> after both partials), multiplies by enc, sums over t.
// All 5 streams coalesced; ~5 MB, L2-resident.
__global__ __launch_bounds__(256) void reduce_t_kernel(
    const float* __restrict__ ws, const float* __restrict__ enc,
    float* __restrict__ out) {
    __shared__ float red[8][32];
    const int b = blockIdx.x >> 3;
    const int qc = blockIdx.x & 7;
    const int qlane = threadIdx.x & 31;
    const int tc = threadIdx.x >> 5;         // 0..7
    const int q = qc * 32 + qlane;

    const int base = (b * TT + tc * 16) * DD + q;
    float a0 = 0.f, a1 = 0.f, a2 = 0.f, a3 = 0.f;
    #pragma unroll
    for (int t = 0; t < 16; t += 4) {
        const int i0 = base + (t + 0) * DD;
        const int i1 = base + (t + 1) * DD;
        const int i2 = base + (t + 2) * DD;
        const int i3 = base + (t + 3) * DD;
        a0 += enc[i0] * (ws[i0] + ws[SZ + i0]) / (ws[2 * SZ + i0] + ws[3 * SZ + i0]);
        a1 += enc[i1] * (ws[i1] + ws[SZ + i1]) / (ws[2 * SZ + i1] + ws[3 * SZ + i1]);
        a2 += enc[i2] * (ws[i2] + ws[SZ + i2]) / (ws[2 * SZ + i2] + ws[3 * SZ + i2]);
        a3 += enc[i3] * (ws[i3] + ws[SZ + i3]) / (ws[2 * SZ + i3] + ws[3 * SZ + i3]);
    }
    red[tc][qlane] = (a0 + a1) + (a2 + a3);
    __syncthreads();
    if (tc == 0) {
        float s = 0.f;
        #pragma unroll
        for (int u = 0; u < 8; ++u) s += red[u][qlane];
        out[b * DD + q] = s;
    }
}

extern "C" void kernel_launch(void* const* d_in, const int* in_sizes, int n_in,
                              void* d_out, int out_size, void* d_ws, size_t ws_size,
                              hipStream_t stream) {
    const float* dec = (const float*)d_in[0];  // [B, D] fp32
    const float* enc = (const float*)d_in[1];  // [B, T, D] fp32
    float* out = (float*)d_out;                // [B, D] fp32
    float* ws = (float*)d_ws;                  // >= 4*BT*DD floats (4 MB)

    attn_hybrid_kernel<<<BT * 2, 256, 0, stream>>>(dec, enc, ws);
    reduce_t_kernel<<<BB * 8, 256, 0, stream>>>(ws, enc, out);
}